// Round 4
// baseline (796.261 us; speedup 1.0000x reference)
//
#include <hip/hip_runtime.h>
#include <hip/hip_bf16.h>
#include <cstdint>

// ---------------------------------------------------------------------------
// RNN_11828339933262: h = x @ w_in^T + b_in ; s_t = tanh(s_{t-1} @ W_n + h_t)
//                     y = rmsnorm(s) * norm_weight ; out = y @ w_out^T
// B=4 S=2048 D=2048 N_HEADS=32 HD=64.  All I/O f32; internal GEMMs bf16 MFMA.
// R7: scan — move the 64x64 matvec from VALU to the MFMA pipe. Cycle model
// (fit on R3/R4/R6): step = 120 roundtrip + 12/ds_read_b128 + ~6/dot2 + tanh,
// fully serialized; the 32 dot2s (~192 cy) dominate. Replace with 8
// v_mfma_f32_16x16x32_f16 (~5 cy each): A = s broadcast-replicated into all
// 16 rows (each lane reads its 8-value k-chunk -> only 2 ds_read_b128/step),
// B = W preloaded in VGPRs (4 col-tiles x K=64). All 16 D rows equal z, so
// lane l picks z[l] = acc[l>>4][0] via 3 cndmasks, + x, ONE tanh, one
// ds_write_b16 to slot l. Fragment layouts mirrored from gemm_nt below
// (same file, harness-verified). Predicted step ~450 -> ~270 cyc.
// ---------------------------------------------------------------------------

typedef short bf16x8 __attribute__((ext_vector_type(8)));   // 8 bf16 = 4 VGPRs
typedef _Float16 f16x8 __attribute__((ext_vector_type(8))); // 8 fp16 = 4 VGPRs
typedef float f32x4 __attribute__((ext_vector_type(4)));

#define GLD16(gp, lp)                                                          \
  __builtin_amdgcn_global_load_lds(                                            \
      (const __attribute__((address_space(1))) void*)(gp),                     \
      (__attribute__((address_space(3))) void*)(lp), 16, 0, 0)

// ---------------------------- f32 -> bf16 convert --------------------------
__global__ __launch_bounds__(256) void cvt_f32_bf16(
    const float* __restrict__ in, __hip_bfloat16* __restrict__ out, int n4) {
  int i = blockIdx.x * 256 + threadIdx.x;
  if (i >= n4) return;
  float4 v = ((const float4*)in)[i];
  __hip_bfloat16 a = __float2bfloat16(v.x);
  __hip_bfloat16 b = __float2bfloat16(v.y);
  __hip_bfloat16 c = __float2bfloat16(v.z);
  __hip_bfloat16 d = __float2bfloat16(v.w);
  ushort4 p;
  p.x = *(unsigned short*)&a; p.y = *(unsigned short*)&b;
  p.z = *(unsigned short*)&c; p.w = *(unsigned short*)&d;
  ((ushort4*)out)[i] = p;
}

// ------------------------------- NT GEMM ------------------------------------
__global__ __launch_bounds__(256) void gemm_nt(
    const __hip_bfloat16* __restrict__ A, const __hip_bfloat16* __restrict__ B,
    const float* __restrict__ bias, float* __restrict__ C,
    int M, int N, int K) {
  __shared__ __hip_bfloat16 As[128 * 32];
  __shared__ __hip_bfloat16 Bs[128 * 32];
  const int tid  = threadIdx.x;
  const int lane = tid & 63;
  const int wave = tid >> 6;
  const int wm = wave >> 1, wn = wave & 1;
  const long bm = (long)blockIdx.y * 128;
  const long bn = (long)blockIdx.x * 128;

  const int c0 = tid, c1 = tid + 256;
  const int r0 = c0 >> 2, k0 = (c0 & 3) * 8;
  const int r1 = c1 >> 2, k1 = (c1 & 3) * 8;
  __hip_bfloat16* lA0 = &As[(wave * 64) * 8];
  __hip_bfloat16* lA1 = &As[(256 + wave * 64) * 8];
  __hip_bfloat16* lB0 = &Bs[(wave * 64) * 8];
  __hip_bfloat16* lB1 = &Bs[(256 + wave * 64) * 8];
  const __hip_bfloat16* gA0 = A + (bm + r0) * (long)K + k0;
  const __hip_bfloat16* gA1 = A + (bm + r1) * (long)K + k1;
  const __hip_bfloat16* gB0 = B + (bn + r0) * (long)K + k0;
  const __hip_bfloat16* gB1 = B + (bn + r1) * (long)K + k1;

  const int fr = lane & 15;
  const int fk = (lane >> 4) * 8;

  f32x4 acc[4][4];
#pragma unroll
  for (int i = 0; i < 4; i++)
#pragma unroll
    for (int j = 0; j < 4; j++) acc[i][j] = {0.f, 0.f, 0.f, 0.f};

  for (int kt = 0; kt < K; kt += 32) {
    __syncthreads();
    GLD16(gA0 + kt, lA0);
    GLD16(gA1 + kt, lA1);
    GLD16(gB0 + kt, lB0);
    GLD16(gB1 + kt, lB1);
    __syncthreads();
    bf16x8 af[4], bfr[4];
#pragma unroll
    for (int t = 0; t < 4; t++)
      af[t] = *(const bf16x8*)&As[(wm * 64 + t * 16 + fr) * 32 + fk];
#pragma unroll
    for (int t = 0; t < 4; t++)
      bfr[t] = *(const bf16x8*)&Bs[(wn * 64 + t * 16 + fr) * 32 + fk];
#pragma unroll
    for (int i = 0; i < 4; i++)
#pragma unroll
      for (int j = 0; j < 4; j++)
        acc[i][j] = __builtin_amdgcn_mfma_f32_16x16x32_bf16(
            af[i], bfr[j], acc[i][j], 0, 0, 0);
  }

  const int cr = (lane >> 4) * 4;
  const int cc = lane & 15;
#pragma unroll
  for (int j = 0; j < 4; j++) {
    const long n = bn + wn * 64 + j * 16 + cc;
    const float bv = bias ? bias[n] : 0.0f;
#pragma unroll
    for (int i = 0; i < 4; i++) {
      const long m = bm + wm * 64 + i * 16 + cr;
#pragma unroll
      for (int r = 0; r < 4; r++)
        C[(m + r) * (long)N + n] = acc[i][j][r] + bv;
    }
  }
}

// ------------------------------- RNN scan -----------------------------------
// One wave per (batch, head) chain; lane l owns output l. Per step:
//   A-frags (s replicated into all 16 MFMA rows): 2 ds_read_b128 from the
//   128 B fp16 state buffer (lane l reads chunk g = l>>4);
//   8 x mfma_f32_16x16x32_f16 against preloaded W fragments (B operand);
//   z[l] = acc[g][0] via 3 loop-invariant-mask cndmasks; + x; tanh;
//   ds_write_b16 s_h[l]; issue next step's 2 reads; global store (off-path).
// Single-wave block + in-order DS pipe -> no waitcnt between write and the
// broadcast reads; MFMA latency replaces 32 VALU dot2s (~192 -> ~45 cyc).
__device__ __forceinline__ float tanh_fast(float z) {
  // tanh(z) = 1 - 2/(e^{2z}+1); e^{2z} = 2^(z * 2*log2(e)) — one mul + v_exp.
  float e = __builtin_amdgcn_exp2f(z * 2.8853900817779268f);
  return 1.0f - 2.0f * __builtin_amdgcn_rcpf(e + 1.0f);
}

__global__ __launch_bounds__(64) void scan_kernel(
    const float* __restrict__ Wst, float* __restrict__ h) {
  const int b = blockIdx.x >> 5;    // 0..3
  const int n = blockIdx.x & 31;    // 0..31
  const int lane = threadIdx.x;     // 0..63
  const int g = lane >> 4;          // k-chunk group / output tile select
  const int c = lane & 15;          // column within tile
  const float* Wn = Wst + n * 4096; // W[h][k], k contiguous (64x64)

  // B fragments (mirrors gemm_nt's B layout: lane -> col c, k = g*8+i):
  // bfr[j][kk][i] = W[kk*32 + g*8 + i][j*16 + c], fp16.
  f16x8 bfr[4][2];
#pragma unroll
  for (int j = 0; j < 4; j++)
#pragma unroll
    for (int kk = 0; kk < 2; kk++) {
      f16x8 t;
#pragma unroll
      for (int i = 0; i < 8; i++)
        t[i] = (_Float16)Wn[(kk * 32 + g * 8 + i) * 64 + j * 16 + c];
      bfr[j][kk] = t;
    }

  __shared__ alignas(16) unsigned short s_h[64];  // 128 B fp16 state

  // A fragments for the upcoming step; s_0 = 0 so start from zero regs.
  f16x8 a0, a1;
#pragma unroll
  for (int i = 0; i < 8; i++) { a0[i] = (_Float16)0.f; a1[i] = (_Float16)0.f; }

  float* hp = h + ((size_t)b * 2048) * 2048 + n * 64 + lane;  // t-stride 2048
  float xcur[8], xnxt[8];
#pragma unroll
  for (int i = 0; i < 8; i++) xcur[i] = hp[(size_t)i * 2048];

  for (int t0 = 0; t0 < 2048; t0 += 8) {
    if (t0 + 8 < 2048) {
#pragma unroll
      for (int i = 0; i < 8; i++)
        xnxt[i] = hp[(size_t)(t0 + 8 + i) * 2048];
    }
#pragma unroll
    for (int i = 0; i < 8; i++) {
      // z = s_{t-1} @ W (+x): 4 independent col-tiles x 2 K-halves on the
      // MFMA pipe. A rows are all s, so every D row equals z_tile.
      const f32x4 zer = {0.f, 0.f, 0.f, 0.f};
      f32x4 ac0 = __builtin_amdgcn_mfma_f32_16x16x32_f16(a0, bfr[0][0], zer, 0, 0, 0);
      f32x4 ac1 = __builtin_amdgcn_mfma_f32_16x16x32_f16(a0, bfr[1][0], zer, 0, 0, 0);
      f32x4 ac2 = __builtin_amdgcn_mfma_f32_16x16x32_f16(a0, bfr[2][0], zer, 0, 0, 0);
      f32x4 ac3 = __builtin_amdgcn_mfma_f32_16x16x32_f16(a0, bfr[3][0], zer, 0, 0, 0);
      ac0 = __builtin_amdgcn_mfma_f32_16x16x32_f16(a1, bfr[0][1], ac0, 0, 0, 0);
      ac1 = __builtin_amdgcn_mfma_f32_16x16x32_f16(a1, bfr[1][1], ac1, 0, 0, 0);
      ac2 = __builtin_amdgcn_mfma_f32_16x16x32_f16(a1, bfr[2][1], ac2, 0, 0, 0);
      ac3 = __builtin_amdgcn_mfma_f32_16x16x32_f16(a1, bfr[3][1], ac3, 0, 0, 0);
      // Lane l's output index is l = 16*g + c: tile g, column c -> acc[g][0].
      // Masks (g&1, g&2) are loop-invariant; 3 cndmasks on the path.
      float zlo = (g & 1) ? ac1[0] : ac0[0];
      float zhi = (g & 1) ? ac3[0] : ac2[0];
      float z = ((g & 2) ? zhi : zlo) + xcur[i];
      float sn = tanh_fast(z);
      // Broadcast s_t for step t+1: one b16 write then 2 b128 chunk reads —
      // DS pipe is in-order per wave, no waitcnt needed between.
      _Float16 sh = (_Float16)sn;
      s_h[lane] = __builtin_bit_cast(unsigned short, sh);
      a0 = *(const f16x8*)&s_h[g * 8];
      a1 = *(const f16x8*)&s_h[32 + g * 8];
      hp[(size_t)(t0 + i) * 2048] = sn;   // fire-and-forget, off the path
    }
#pragma unroll
    for (int i = 0; i < 8; i++) xcur[i] = xnxt[i];
  }
}

// --------------------------- RMSNorm -> bf16 --------------------------------
__global__ __launch_bounds__(256) void rmsnorm_to_bf16(
    const float* __restrict__ Y, const float* __restrict__ g,
    __hip_bfloat16* __restrict__ O) {
  const long row = blockIdx.x;
  const float* yr = Y + row * 2048;
  const int tid = threadIdx.x;
  float4 v0 = ((const float4*)yr)[tid * 2];
  float4 v1 = ((const float4*)yr)[tid * 2 + 1];
  float ss = v0.x * v0.x + v0.y * v0.y + v0.z * v0.z + v0.w * v0.w +
             v1.x * v1.x + v1.y * v1.y + v1.z * v1.z + v1.w * v1.w;
#pragma unroll
  for (int off = 32; off > 0; off >>= 1) ss += __shfl_down(ss, off);
  __shared__ float red[4];
  if ((tid & 63) == 0) red[tid >> 6] = ss;
  __syncthreads();
  float inv = rsqrtf((red[0] + red[1] + red[2] + red[3]) * (1.0f / 2048.0f)
                     + 1e-6f);
  float4 g0 = ((const float4*)(g + tid * 8))[0];
  float4 g1 = ((const float4*)(g + tid * 8))[1];
  float ov[8] = {v0.x * inv * g0.x, v0.y * inv * g0.y,
                 v0.z * inv * g0.z, v0.w * inv * g0.w,
                 v1.x * inv * g1.x, v1.y * inv * g1.y,
                 v1.z * inv * g1.z, v1.w * inv * g1.w};
  ushort4 p0, p1;
  __hip_bfloat16 t;
  t = __float2bfloat16(ov[0]); p0.x = *(unsigned short*)&t;
  t = __float2bfloat16(ov[1]); p0.y = *(unsigned short*)&t;
  t = __float2bfloat16(ov[2]); p0.z = *(unsigned short*)&t;
  t = __float2bfloat16(ov[3]); p0.w = *(unsigned short*)&t;
  t = __float2bfloat16(ov[4]); p1.x = *(unsigned short*)&t;
  t = __float2bfloat16(ov[5]); p1.y = *(unsigned short*)&t;
  t = __float2bfloat16(ov[6]); p1.z = *(unsigned short*)&t;
  t = __float2bfloat16(ov[7]); p1.w = *(unsigned short*)&t;
  ushort4* op = (ushort4*)(O + row * 2048 + tid * 8);
  op[0] = p0;
  op[1] = p1;
}

// ------------------------------- launch -------------------------------------
extern "C" void kernel_launch(void* const* d_in, const int* in_sizes, int n_in,
                              void* d_out, int out_size, void* d_ws,
                              size_t ws_size, hipStream_t stream) {
  const float* x     = (const float*)d_in[0];  // (4,2048,2048)
  const float* w_in  = (const float*)d_in[1];  // (2048,2048)
  const float* b_in  = (const float*)d_in[2];  // (2048,)
  const float* w_st  = (const float*)d_in[3];  // (32,64,64)
  const float* nw    = (const float*)d_in[4];  // (2048,)
  const float* w_out = (const float*)d_in[5];  // (2048,2048)
  float* out = (float*)d_out;

  char* ws = (char*)d_ws;
  __hip_bfloat16* x_bf  = (__hip_bfloat16*)(ws);              // 33,554,432 B
  __hip_bfloat16* wi_bf = (__hip_bfloat16*)(ws + 33554432);   //  8,388,608 B
  __hip_bfloat16* wo_bf = (__hip_bfloat16*)(ws + 41943040);   //  8,388,608 B
  float* h              = (float*)(ws + 50331648);            // 67,108,864 B
  // x_bf buffer is reused for the rmsnorm'ed bf16 states (same size).

  cvt_f32_bf16<<<16384, 256, 0, stream>>>(x, x_bf, 4194304);
  cvt_f32_bf16<<<4096, 256, 0, stream>>>(w_in, wi_bf, 1048576);
  cvt_f32_bf16<<<4096, 256, 0, stream>>>(w_out, wo_bf, 1048576);

  // h = x @ w_in^T + b_in   (M=8192, N=2048, K=2048)
  gemm_nt<<<dim3(16, 64), 256, 0, stream>>>(x_bf, wi_bf, b_in, h,
                                            8192, 2048, 2048);
  // in-place tanh recurrence per (batch, head)
  scan_kernel<<<128, 64, 0, stream>>>(w_st, h);
  // rmsnorm + cast to bf16 (into x_bf buffer)
  rmsnorm_to_bf16<<<8192, 256, 0, stream>>>(h, nw, x_bf);
  // out = y_norm @ w_out^T
  gemm_nt<<<dim3(16, 64), 256, 0, stream>>>(x_bf, wo_bf, nullptr, out,
                                            8192, 2048, 2048);
}

// Round 6
// 759.856 us; speedup vs baseline: 1.0479x; 1.0479x over previous
//
#include <hip/hip_runtime.h>
#include <hip/hip_bf16.h>
#include <cstdint>

// ---------------------------------------------------------------------------
// RNN_11828339933262: h = x @ w_in^T + b_in ; s_t = tanh(s_{t-1} @ W_n + h_t)
//                     y = rmsnorm(s) * norm_weight ; out = y @ w_out^T
// B=4 S=2048 D=2048 N_HEADS=32 HD=64.  All I/O f32; internal GEMMs bf16 MFMA.
// R9: scan — R6 structure (454 cyc/step fit: 116 roundtrip + 96 reads +
// 182 dot2 + 60 tanh/misc). Single change on the serial path: the 32 dot2s
// (measured ~5.7cy) -> 32 v_pk_fma_f16 via __builtin_elementwise_fma on
// f16x2 (NO inline asm — both container failures, R5/R8, introduced new asm
// mnemonics; builtins only from here). 4 independent accumulator chains,
// reads consumed in sv[q] order for progressive lgkmcnt. k-split dropped:
// its shfl_xor is a serial DS op (~120cy) costing more than the 48cy of
// reads it saves. GEMM: bijective XCD-chunked remap (bn-major chunks) so
// each XCD's B-panel (1MB) stays L2-resident (T1; 1024 blocks % 8 == 0).
// ---------------------------------------------------------------------------

typedef short bf16x8 __attribute__((ext_vector_type(8)));   // 8 bf16 = 4 VGPRs
typedef float f32x4 __attribute__((ext_vector_type(4)));
typedef _Float16 f16x2 __attribute__((ext_vector_type(2))); // 1 VGPR

#define GLD16(gp, lp)                                                          \
  __builtin_amdgcn_global_load_lds(                                            \
      (const __attribute__((address_space(1))) void*)(gp),                     \
      (__attribute__((address_space(3))) void*)(lp), 16, 0, 0)

// ---------------------------- f32 -> bf16 convert --------------------------
__global__ __launch_bounds__(256) void cvt_f32_bf16(
    const float* __restrict__ in, __hip_bfloat16* __restrict__ out, int n4) {
  int i = blockIdx.x * 256 + threadIdx.x;
  if (i >= n4) return;
  float4 v = ((const float4*)in)[i];
  __hip_bfloat16 a = __float2bfloat16(v.x);
  __hip_bfloat16 b = __float2bfloat16(v.y);
  __hip_bfloat16 c = __float2bfloat16(v.z);
  __hip_bfloat16 d = __float2bfloat16(v.w);
  ushort4 p;
  p.x = *(unsigned short*)&a; p.y = *(unsigned short*)&b;
  p.z = *(unsigned short*)&c; p.w = *(unsigned short*)&d;
  ((ushort4*)out)[i] = p;
}

// ------------------------------- NT GEMM ------------------------------------
__global__ __launch_bounds__(256) void gemm_nt(
    const __hip_bfloat16* __restrict__ A, const __hip_bfloat16* __restrict__ B,
    const float* __restrict__ bias, float* __restrict__ C,
    int M, int N, int K) {
  __shared__ __hip_bfloat16 As[128 * 32];
  __shared__ __hip_bfloat16 Bs[128 * 32];
  const int tid  = threadIdx.x;
  const int lane = tid & 63;
  const int wave = tid >> 6;
  const int wm = wave >> 1, wn = wave & 1;

  // XCD-chunked bijective remap (nwg % 8 == 0): flat id -> v such that each
  // XCD (id%8) owns a contiguous bn-major chunk -> its B-panels stay in its
  // private L2. bn = v / gridDim.y, bm = v % gridDim.y.
  const int id = blockIdx.y * gridDim.x + blockIdx.x;
  const int chunk = (gridDim.x * gridDim.y) >> 3;
  const int v = (id & 7) * chunk + (id >> 3);
  const int vbn = v / gridDim.y;
  const int vbm = v - vbn * gridDim.y;
  const long bm = (long)vbm * 128;
  const long bn = (long)vbn * 128;

  const int c0 = tid, c1 = tid + 256;
  const int r0 = c0 >> 2, k0 = (c0 & 3) * 8;
  const int r1 = c1 >> 2, k1 = (c1 & 3) * 8;
  __hip_bfloat16* lA0 = &As[(wave * 64) * 8];
  __hip_bfloat16* lA1 = &As[(256 + wave * 64) * 8];
  __hip_bfloat16* lB0 = &Bs[(wave * 64) * 8];
  __hip_bfloat16* lB1 = &Bs[(256 + wave * 64) * 8];
  const __hip_bfloat16* gA0 = A + (bm + r0) * (long)K + k0;
  const __hip_bfloat16* gA1 = A + (bm + r1) * (long)K + k1;
  const __hip_bfloat16* gB0 = B + (bn + r0) * (long)K + k0;
  const __hip_bfloat16* gB1 = B + (bn + r1) * (long)K + k1;

  const int fr = lane & 15;
  const int fk = (lane >> 4) * 8;

  f32x4 acc[4][4];
#pragma unroll
  for (int i = 0; i < 4; i++)
#pragma unroll
    for (int j = 0; j < 4; j++) acc[i][j] = {0.f, 0.f, 0.f, 0.f};

  for (int kt = 0; kt < K; kt += 32) {
    __syncthreads();
    GLD16(gA0 + kt, lA0);
    GLD16(gA1 + kt, lA1);
    GLD16(gB0 + kt, lB0);
    GLD16(gB1 + kt, lB1);
    __syncthreads();
    bf16x8 af[4], bfr[4];
#pragma unroll
    for (int t = 0; t < 4; t++)
      af[t] = *(const bf16x8*)&As[(wm * 64 + t * 16 + fr) * 32 + fk];
#pragma unroll
    for (int t = 0; t < 4; t++)
      bfr[t] = *(const bf16x8*)&Bs[(wn * 64 + t * 16 + fr) * 32 + fk];
#pragma unroll
    for (int i = 0; i < 4; i++)
#pragma unroll
      for (int j = 0; j < 4; j++)
        acc[i][j] = __builtin_amdgcn_mfma_f32_16x16x32_bf16(
            af[i], bfr[j], acc[i][j], 0, 0, 0);
  }

  const int cr = (lane >> 4) * 4;
  const int cc = lane & 15;
#pragma unroll
  for (int j = 0; j < 4; j++) {
    const long n = bn + wn * 64 + j * 16 + cc;
    const float bv = bias ? bias[n] : 0.0f;
#pragma unroll
    for (int i = 0; i < 4; i++) {
      const long m = bm + wm * 64 + i * 16 + cr;
#pragma unroll
      for (int r = 0; r < 4; r++)
        C[(m + r) * (long)N + n] = acc[i][j][r] + bv;
    }
  }
}

// ------------------------------- RNN scan -----------------------------------
// One wave per (batch, head) chain; lane k owns output k. State broadcast in
// FP16 through a 128-byte LDS buffer: lane writes its new value (b16), then
// all lanes read the full state with 8 ds_read_b128 (same-address broadcast,
// conflict-free). Matvec: 32 v_pk_fma_f16 (via __builtin_elementwise_fma on
// f16x2 — llvm.fma.v2f16, no inline asm) against pre-packed fp16 weight
// pairs held in VGPRs; 4 independent accumulator chains. Single-wave block +
// in-order DS pipe -> no waitcnt between write and the broadcast reads;
// compiler gates each FMA on its read with fine-grained lgkmcnt.
__device__ __forceinline__ float tanh_fast(float z) {
  // tanh(z) = 1 - 2/(e^{2z}+1); e^{2z} = 2^(z * 2*log2(e)) — one mul + v_exp.
  float e = __builtin_amdgcn_exp2f(z * 2.8853900817779268f);
  return 1.0f - 2.0f * __builtin_amdgcn_rcpf(e + 1.0f);
}

__global__ __launch_bounds__(64) void scan_kernel(
    const float* __restrict__ Wst, float* __restrict__ h) {
  const int b = blockIdx.x >> 5;    // 0..3
  const int n = blockIdx.x & 31;    // 0..31
  const int lane = threadIdx.x;     // 0..63
  const float* Wn = Wst + n * 4096; // W[k][j] = Wn[k*64 + j], j contiguous

  // Packed fp16 weight pairs over the contraction dim:
  // w2[p] = (W[2p][lane], W[2p+1][lane]).
  f16x2 w2[32];
#pragma unroll
  for (int p = 0; p < 32; p++) {
    f16x2 t;
    t.x = (_Float16)Wn[(2 * p) * 64 + lane];
    t.y = (_Float16)Wn[(2 * p + 1) * 64 + lane];
    w2[p] = t;
  }

  __shared__ alignas(16) unsigned short s_h[64];  // 128 B fp16 state

  // Packed state dwords for the upcoming step; s_0 = 0 (fp16 zero = 0x0000),
  // so start from zero registers (first write precedes first read).
  int4 sv[8];
#pragma unroll
  for (int q = 0; q < 8; q++) sv[q] = make_int4(0, 0, 0, 0);

  float* hp = h + ((size_t)b * 2048) * 2048 + n * 64 + lane;  // t-stride 2048
  float xcur[8], xnxt[8];
#pragma unroll
  for (int i = 0; i < 8; i++) xcur[i] = hp[(size_t)i * 2048];

  const f16x2 z2 = {(_Float16)0.f, (_Float16)0.f};

  for (int t0 = 0; t0 < 2048; t0 += 8) {
    if (t0 + 8 < 2048) {
#pragma unroll
      for (int i = 0; i < 8; i++)
        xnxt[i] = hp[(size_t)(t0 + 8 + i) * 2048];
    }
#pragma unroll
    for (int i = 0; i < 8; i++) {
      // z = dot(s_{t-1}, W[:,lane]) + x_t ; 4 independent pk_fma_f16 chains,
      // consumed in read-return order (sv[q] ascending) so the compiler's
      // progressive lgkmcnt lets FMAs start as reads land.
      f16x2 ac0 = z2, ac1 = z2, ac2 = z2, ac3 = z2;
#pragma unroll
      for (int q = 0; q < 8; q++) {
        ac0 = __builtin_elementwise_fma(__builtin_bit_cast(f16x2, sv[q].x),
                                        w2[4 * q + 0], ac0);
        ac1 = __builtin_elementwise_fma(__builtin_bit_cast(f16x2, sv[q].y),
                                        w2[4 * q + 1], ac1);
        ac2 = __builtin_elementwise_fma(__builtin_bit_cast(f16x2, sv[q].z),
                                        w2[4 * q + 2], ac2);
        ac3 = __builtin_elementwise_fma(__builtin_bit_cast(f16x2, sv[q].w),
                                        w2[4 * q + 3], ac3);
      }
      f16x2 p01 = ac0 + ac1;             // v_pk_add_f16
      f16x2 p23 = ac2 + ac3;
      f16x2 pt = p01 + p23;
      float z = (float)pt.x + (float)pt.y + xcur[i];
      float sn = tanh_fast(z);
      // Broadcast s_t for step t+1: one b16 write then 8 b128 broadcast
      // reads — DS pipe is in-order per wave, no waitcnt needed between.
      _Float16 sh = (_Float16)sn;
      s_h[lane] = __builtin_bit_cast(unsigned short, sh);
#pragma unroll
      for (int q = 0; q < 8; q++) sv[q] = ((const int4*)s_h)[q];
      hp[(size_t)(t0 + i) * 2048] = sn;   // fire-and-forget, off the path
    }
#pragma unroll
    for (int i = 0; i < 8; i++) xcur[i] = xnxt[i];
  }
}

// --------------------------- RMSNorm -> bf16 --------------------------------
__global__ __launch_bounds__(256) void rmsnorm_to_bf16(
    const float* __restrict__ Y, const float* __restrict__ g,
    __hip_bfloat16* __restrict__ O) {
  const long row = blockIdx.x;
  const float* yr = Y + row * 2048;
  const int tid = threadIdx.x;
  float4 v0 = ((const float4*)yr)[tid * 2];
  float4 v1 = ((const float4*)yr)[tid * 2 + 1];
  float ss = v0.x * v0.x + v0.y * v0.y + v0.z * v0.z + v0.w * v0.w +
             v1.x * v1.x + v1.y * v1.y + v1.z * v1.z + v1.w * v1.w;
#pragma unroll
  for (int off = 32; off > 0; off >>= 1) ss += __shfl_down(ss, off);
  __shared__ float red[4];
  if ((tid & 63) == 0) red[tid >> 6] = ss;
  __syncthreads();
  float inv = rsqrtf((red[0] + red[1] + red[2] + red[3]) * (1.0f / 2048.0f)
                     + 1e-6f);
  float4 g0 = ((const float4*)(g + tid * 8))[0];
  float4 g1 = ((const float4*)(g + tid * 8))[1];
  float ov[8] = {v0.x * inv * g0.x, v0.y * inv * g0.y,
                 v0.z * inv * g0.z, v0.w * inv * g0.w,
                 v1.x * inv * g1.x, v1.y * inv * g1.y,
                 v1.z * inv * g1.z, v1.w * inv * g1.w};
  ushort4 p0, p1;
  __hip_bfloat16 t;
  t = __float2bfloat16(ov[0]); p0.x = *(unsigned short*)&t;
  t = __float2bfloat16(ov[1]); p0.y = *(unsigned short*)&t;
  t = __float2bfloat16(ov[2]); p0.z = *(unsigned short*)&t;
  t = __float2bfloat16(ov[3]); p0.w = *(unsigned short*)&t;
  t = __float2bfloat16(ov[4]); p1.x = *(unsigned short*)&t;
  t = __float2bfloat16(ov[5]); p1.y = *(unsigned short*)&t;
  t = __float2bfloat16(ov[6]); p1.z = *(unsigned short*)&t;
  t = __float2bfloat16(ov[7]); p1.w = *(unsigned short*)&t;
  ushort4* op = (ushort4*)(O + row * 2048 + tid * 8);
  op[0] = p0;
  op[1] = p1;
}

// ------------------------------- launch -------------------------------------
extern "C" void kernel_launch(void* const* d_in, const int* in_sizes, int n_in,
                              void* d_out, int out_size, void* d_ws,
                              size_t ws_size, hipStream_t stream) {
  const float* x     = (const float*)d_in[0];  // (4,2048,2048)
  const float* w_in  = (const float*)d_in[1];  // (2048,2048)
  const float* b_in  = (const float*)d_in[2];  // (2048,)
  const float* w_st  = (const float*)d_in[3];  // (32,64,64)
  const float* nw    = (const float*)d_in[4];  // (2048,)
  const float* w_out = (const float*)d_in[5];  // (2048,2048)
  float* out = (float*)d_out;

  char* ws = (char*)d_ws;
  __hip_bfloat16* x_bf  = (__hip_bfloat16*)(ws);              // 33,554,432 B
  __hip_bfloat16* wi_bf = (__hip_bfloat16*)(ws + 33554432);   //  8,388,608 B
  __hip_bfloat16* wo_bf = (__hip_bfloat16*)(ws + 41943040);   //  8,388,608 B
  float* h              = (float*)(ws + 50331648);            // 67,108,864 B
  // x_bf buffer is reused for the rmsnorm'ed bf16 states (same size).

  cvt_f32_bf16<<<16384, 256, 0, stream>>>(x, x_bf, 4194304);
  cvt_f32_bf16<<<4096, 256, 0, stream>>>(w_in, wi_bf, 1048576);
  cvt_f32_bf16<<<4096, 256, 0, stream>>>(w_out, wo_bf, 1048576);

  // h = x @ w_in^T + b_in   (M=8192, N=2048, K=2048)
  gemm_nt<<<dim3(16, 64), 256, 0, stream>>>(x_bf, wi_bf, b_in, h,
                                            8192, 2048, 2048);
  // in-place tanh recurrence per (batch, head)
  scan_kernel<<<128, 64, 0, stream>>>(w_st, h);
  // rmsnorm + cast to bf16 (into x_bf buffer)
  rmsnorm_to_bf16<<<8192, 256, 0, stream>>>(h, nw, x_bf);
  // out = y_norm @ w_out^T
  gemm_nt<<<dim3(16, 64), 256, 0, stream>>>(x_bf, wo_bf, nullptr, out,
                                            8192, 2048, 2048);
}

// Round 7
// 718.824 us; speedup vs baseline: 1.1077x; 1.0571x over previous
//
#include <hip/hip_runtime.h>
#include <hip/hip_bf16.h>
#include <cstdint>

// ---------------------------------------------------------------------------
// RNN_11828339933262: h = x @ w_in^T + b_in ; s_t = tanh(s_{t-1} @ W_n + h_t)
//                     y = rmsnorm(s) * norm_weight ; out = y @ w_out^T
// B=4 S=2048 D=2048 N_HEADS=32 HD=64.  All I/O f32; internal GEMMs bf16 MFMA.
// R10: GEMM — the scan is near its structural floor (438 cyc/step; op-cost
// law: ~5cy/VALU, ~12cy/ds_read_b128, +116cy roundtrip, fully serial). The
// GEMMs are traffic-bound: 128^2 tiles re-read panels 1073 MB/GEMM =
// ~170us at HBM/L3 ceiling. Move to 256x256 tiles (536 MB, -50%) with the
// verified minimum 2-phase rotation (stage next K-tile into the other LDS
// buffer BEFORE compute; one vmcnt(0)+barrier per K-step) to hide staging
// latency at 1 block/CU. 8 waves (2m x 4n), per-wave 128x64, acc[8][4].
// gridDim.x=8 -> XCD = bn-column naturally; 1MB B-panel L2-resident/XCD.
// K-accumulation order unchanged -> bit-identical output. Scan = R9 (373us).
// ---------------------------------------------------------------------------

typedef short bf16x8 __attribute__((ext_vector_type(8)));   // 8 bf16 = 4 VGPRs
typedef float f32x4 __attribute__((ext_vector_type(4)));
typedef _Float16 f16x2 __attribute__((ext_vector_type(2))); // 1 VGPR

#define GLD16(gp, lp)                                                          \
  __builtin_amdgcn_global_load_lds(                                            \
      (const __attribute__((address_space(1))) void*)(gp),                     \
      (__attribute__((address_space(3))) void*)(lp), 16, 0, 0)

// ---------------------------- f32 -> bf16 convert --------------------------
__global__ __launch_bounds__(256) void cvt_f32_bf16(
    const float* __restrict__ in, __hip_bfloat16* __restrict__ out, int n4) {
  int i = blockIdx.x * 256 + threadIdx.x;
  if (i >= n4) return;
  float4 v = ((const float4*)in)[i];
  __hip_bfloat16 a = __float2bfloat16(v.x);
  __hip_bfloat16 b = __float2bfloat16(v.y);
  __hip_bfloat16 c = __float2bfloat16(v.z);
  __hip_bfloat16 d = __float2bfloat16(v.w);
  ushort4 p;
  p.x = *(unsigned short*)&a; p.y = *(unsigned short*)&b;
  p.z = *(unsigned short*)&c; p.w = *(unsigned short*)&d;
  ((ushort4*)out)[i] = p;
}

// ------------------------------- NT GEMM ------------------------------------
// BM=BN=256, BK=32, 512 threads (8 waves as 2m x 4n), per-wave output 128x64.
// Double-buffered LDS (2 x 16KB per matrix); 2-phase rotation: issue next
// K-tile's global_load_lds before this tile's ds_read+MFMA, then vmcnt(0) +
// one barrier per K-step. Stage writes go to buf^1 while reads hit buf ->
// no overlap; barrier-per-iter protects the buffer swap.
__global__ __launch_bounds__(512) void gemm_nt(
    const __hip_bfloat16* __restrict__ A, const __hip_bfloat16* __restrict__ B,
    const float* __restrict__ bias, float* __restrict__ C,
    int M, int N, int K) {
  __shared__ __hip_bfloat16 As[2][256 * 32];
  __shared__ __hip_bfloat16 Bs[2][256 * 32];
  const int tid  = threadIdx.x;          // 0..511
  const int lane = tid & 63;
  const int wave = tid >> 6;             // 0..7
  const int wm = wave >> 2;              // 0..1  (m half)
  const int wn = wave & 3;               // 0..3  (n quarter)
  const long bm = (long)blockIdx.y * 256;
  const long bn = (long)blockIdx.x * 256;

  // Staging: thread t loads rows r0 = t>>2 and 128+r0, k-chunk (t&3)*8.
  // LDS dest is wave-uniform base + lane*16B (global_load_lds rule); the
  // linear dest order matches row-major [256][32] exactly (verified算):
  // elem w*512 + l*8 == row(w*16 + l>>2)*32 + (l&3)*8.
  const int r0 = tid >> 2;               // 0..127
  const int k0 = (tid & 3) * 8;
  const __hip_bfloat16* gA0 = A + (bm + r0) * (long)K + k0;
  const __hip_bfloat16* gA1 = A + (bm + 128 + r0) * (long)K + k0;
  const __hip_bfloat16* gB0 = B + (bn + r0) * (long)K + k0;
  const __hip_bfloat16* gB1 = B + (bn + 128 + r0) * (long)K + k0;

#define STAGE(sbuf, kt)                                                        \
  do {                                                                         \
    GLD16(gA0 + (kt) * 32, &As[sbuf][wave * 512]);                             \
    GLD16(gA1 + (kt) * 32, &As[sbuf][4096 + wave * 512]);                      \
    GLD16(gB0 + (kt) * 32, &Bs[sbuf][wave * 512]);                             \
    GLD16(gB1 + (kt) * 32, &Bs[sbuf][4096 + wave * 512]);                      \
  } while (0)

  const int fr = lane & 15;
  const int fk = (lane >> 4) * 8;

  f32x4 acc[8][4];
#pragma unroll
  for (int i = 0; i < 8; i++)
#pragma unroll
    for (int j = 0; j < 4; j++) acc[i][j] = {0.f, 0.f, 0.f, 0.f};

  STAGE(0, 0);
  asm volatile("s_waitcnt vmcnt(0)" ::: "memory");
  __syncthreads();

  const int nk = K >> 5;                 // 64 K-steps
  for (int kt = 0; kt < nk; kt++) {
    const int cur = kt & 1;
    if (kt + 1 < nk) STAGE(cur ^ 1, kt + 1);   // prefetch next tile (async)
    bf16x8 af[8], bfr[4];
#pragma unroll
    for (int t = 0; t < 8; t++)
      af[t] = *(const bf16x8*)&As[cur][(wm * 128 + t * 16 + fr) * 32 + fk];
#pragma unroll
    for (int t = 0; t < 4; t++)
      bfr[t] = *(const bf16x8*)&Bs[cur][(wn * 64 + t * 16 + fr) * 32 + fk];
#pragma unroll
    for (int i = 0; i < 8; i++)
#pragma unroll
      for (int j = 0; j < 4; j++)
        acc[i][j] = __builtin_amdgcn_mfma_f32_16x16x32_bf16(
            af[i], bfr[j], acc[i][j], 0, 0, 0);
    asm volatile("s_waitcnt vmcnt(0)" ::: "memory");  // next-buf loads landed
    __syncthreads();                     // safe to overwrite buf[cur] next it
  }
#undef STAGE

  const int cr = (lane >> 4) * 4;
  const int cc = lane & 15;
#pragma unroll
  for (int j = 0; j < 4; j++) {
    const long n = bn + wn * 64 + j * 16 + cc;
    const float bv = bias ? bias[n] : 0.0f;
#pragma unroll
    for (int i = 0; i < 8; i++) {
      const long m = bm + wm * 128 + i * 16 + cr;
#pragma unroll
      for (int r = 0; r < 4; r++)
        C[(m + r) * (long)N + n] = acc[i][j][r] + bv;
    }
  }
}

// ------------------------------- RNN scan -----------------------------------
// One wave per (batch, head) chain; lane k owns output k. State broadcast in
// FP16 through a 128-byte LDS buffer: lane writes its new value (b16), then
// all lanes read the full state with 8 ds_read_b128 (same-address broadcast,
// conflict-free). Matvec: 32 v_pk_fma_f16 (via __builtin_elementwise_fma on
// f16x2) against pre-packed fp16 weight pairs held in VGPRs; 4 independent
// accumulator chains. Single-wave block + in-order DS pipe -> no waitcnt
// between write and the broadcast reads.
__device__ __forceinline__ float tanh_fast(float z) {
  // tanh(z) = 1 - 2/(e^{2z}+1); e^{2z} = 2^(z * 2*log2(e)) — one mul + v_exp.
  float e = __builtin_amdgcn_exp2f(z * 2.8853900817779268f);
  return 1.0f - 2.0f * __builtin_amdgcn_rcpf(e + 1.0f);
}

__global__ __launch_bounds__(64) void scan_kernel(
    const float* __restrict__ Wst, float* __restrict__ h) {
  const int b = blockIdx.x >> 5;    // 0..3
  const int n = blockIdx.x & 31;    // 0..31
  const int lane = threadIdx.x;     // 0..63
  const float* Wn = Wst + n * 4096; // W[k][j] = Wn[k*64 + j], j contiguous

  // Packed fp16 weight pairs over the contraction dim:
  // w2[p] = (W[2p][lane], W[2p+1][lane]).
  f16x2 w2[32];
#pragma unroll
  for (int p = 0; p < 32; p++) {
    f16x2 t;
    t.x = (_Float16)Wn[(2 * p) * 64 + lane];
    t.y = (_Float16)Wn[(2 * p + 1) * 64 + lane];
    w2[p] = t;
  }

  __shared__ alignas(16) unsigned short s_h[64];  // 128 B fp16 state

  int4 sv[8];
#pragma unroll
  for (int q = 0; q < 8; q++) sv[q] = make_int4(0, 0, 0, 0);

  float* hp = h + ((size_t)b * 2048) * 2048 + n * 64 + lane;  // t-stride 2048
  float xcur[8], xnxt[8];
#pragma unroll
  for (int i = 0; i < 8; i++) xcur[i] = hp[(size_t)i * 2048];

  const f16x2 z2 = {(_Float16)0.f, (_Float16)0.f};

  for (int t0 = 0; t0 < 2048; t0 += 8) {
    if (t0 + 8 < 2048) {
#pragma unroll
      for (int i = 0; i < 8; i++)
        xnxt[i] = hp[(size_t)(t0 + 8 + i) * 2048];
    }
#pragma unroll
    for (int i = 0; i < 8; i++) {
      // z = dot(s_{t-1}, W[:,lane]) + x_t ; 4 independent pk_fma_f16 chains,
      // consumed in read-return order (sv[q] ascending).
      f16x2 ac0 = z2, ac1 = z2, ac2 = z2, ac3 = z2;
#pragma unroll
      for (int q = 0; q < 8; q++) {
        ac0 = __builtin_elementwise_fma(__builtin_bit_cast(f16x2, sv[q].x),
                                        w2[4 * q + 0], ac0);
        ac1 = __builtin_elementwise_fma(__builtin_bit_cast(f16x2, sv[q].y),
                                        w2[4 * q + 1], ac1);
        ac2 = __builtin_elementwise_fma(__builtin_bit_cast(f16x2, sv[q].z),
                                        w2[4 * q + 2], ac2);
        ac3 = __builtin_elementwise_fma(__builtin_bit_cast(f16x2, sv[q].w),
                                        w2[4 * q + 3], ac3);
      }
      f16x2 p01 = ac0 + ac1;             // v_pk_add_f16
      f16x2 p23 = ac2 + ac3;
      f16x2 pt = p01 + p23;
      float z = (float)pt.x + (float)pt.y + xcur[i];
      float sn = tanh_fast(z);
      // Broadcast s_t for step t+1: one b16 write then 8 b128 broadcast
      // reads — DS pipe is in-order per wave, no waitcnt needed between.
      _Float16 sh = (_Float16)sn;
      s_h[lane] = __builtin_bit_cast(unsigned short, sh);
#pragma unroll
      for (int q = 0; q < 8; q++) sv[q] = ((const int4*)s_h)[q];
      hp[(size_t)(t0 + i) * 2048] = sn;   // fire-and-forget, off the path
    }
#pragma unroll
    for (int i = 0; i < 8; i++) xcur[i] = xnxt[i];
  }
}

// --------------------------- RMSNorm -> bf16 --------------------------------
__global__ __launch_bounds__(256) void rmsnorm_to_bf16(
    const float* __restrict__ Y, const float* __restrict__ g,
    __hip_bfloat16* __restrict__ O) {
  const long row = blockIdx.x;
  const float* yr = Y + row * 2048;
  const int tid = threadIdx.x;
  float4 v0 = ((const float4*)yr)[tid * 2];
  float4 v1 = ((const float4*)yr)[tid * 2 + 1];
  float ss = v0.x * v0.x + v0.y * v0.y + v0.z * v0.z + v0.w * v0.w +
             v1.x * v1.x + v1.y * v1.y + v1.z * v1.z + v1.w * v1.w;
#pragma unroll
  for (int off = 32; off > 0; off >>= 1) ss += __shfl_down(ss, off);
  __shared__ float red[4];
  if ((tid & 63) == 0) red[tid >> 6] = ss;
  __syncthreads();
  float inv = rsqrtf((red[0] + red[1] + red[2] + red[3]) * (1.0f / 2048.0f)
                     + 1e-6f);
  float4 g0 = ((const float4*)(g + tid * 8))[0];
  float4 g1 = ((const float4*)(g + tid * 8))[1];
  float ov[8] = {v0.x * inv * g0.x, v0.y * inv * g0.y,
                 v0.z * inv * g0.z, v0.w * inv * g0.w,
                 v1.x * inv * g1.x, v1.y * inv * g1.y,
                 v1.z * inv * g1.z, v1.w * inv * g1.w};
  ushort4 p0, p1;
  __hip_bfloat16 t;
  t = __float2bfloat16(ov[0]); p0.x = *(unsigned short*)&t;
  t = __float2bfloat16(ov[1]); p0.y = *(unsigned short*)&t;
  t = __float2bfloat16(ov[2]); p0.z = *(unsigned short*)&t;
  t = __float2bfloat16(ov[3]); p0.w = *(unsigned short*)&t;
  t = __float2bfloat16(ov[4]); p1.x = *(unsigned short*)&t;
  t = __float2bfloat16(ov[5]); p1.y = *(unsigned short*)&t;
  t = __float2bfloat16(ov[6]); p1.z = *(unsigned short*)&t;
  t = __float2bfloat16(ov[7]); p1.w = *(unsigned short*)&t;
  ushort4* op = (ushort4*)(O + row * 2048 + tid * 8);
  op[0] = p0;
  op[1] = p1;
}

// ------------------------------- launch -------------------------------------
extern "C" void kernel_launch(void* const* d_in, const int* in_sizes, int n_in,
                              void* d_out, int out_size, void* d_ws,
                              size_t ws_size, hipStream_t stream) {
  const float* x     = (const float*)d_in[0];  // (4,2048,2048)
  const float* w_in  = (const float*)d_in[1];  // (2048,2048)
  const float* b_in  = (const float*)d_in[2];  // (2048,)
  const float* w_st  = (const float*)d_in[3];  // (32,64,64)
  const float* nw    = (const float*)d_in[4];  // (2048,)
  const float* w_out = (const float*)d_in[5];  // (2048,2048)
  float* out = (float*)d_out;

  char* ws = (char*)d_ws;
  __hip_bfloat16* x_bf  = (__hip_bfloat16*)(ws);              // 33,554,432 B
  __hip_bfloat16* wi_bf = (__hip_bfloat16*)(ws + 33554432);   //  8,388,608 B
  __hip_bfloat16* wo_bf = (__hip_bfloat16*)(ws + 41943040);   //  8,388,608 B
  float* h              = (float*)(ws + 50331648);            // 67,108,864 B
  // x_bf buffer is reused for the rmsnorm'ed bf16 states (same size).

  cvt_f32_bf16<<<16384, 256, 0, stream>>>(x, x_bf, 4194304);
  cvt_f32_bf16<<<4096, 256, 0, stream>>>(w_in, wi_bf, 1048576);
  cvt_f32_bf16<<<4096, 256, 0, stream>>>(w_out, wo_bf, 1048576);

  // h = x @ w_in^T + b_in   (M=8192, N=2048, K=2048), 256x256 tiles
  gemm_nt<<<dim3(8, 32), 512, 0, stream>>>(x_bf, wi_bf, b_in, h,
                                           8192, 2048, 2048);
  // in-place tanh recurrence per (batch, head)
  scan_kernel<<<128, 64, 0, stream>>>(w_st, h);
  // rmsnorm + cast to bf16 (into x_bf buffer)
  rmsnorm_to_bf16<<<8192, 256, 0, stream>>>(h, nw, x_bf);
  // out = y_norm @ w_out^T
  gemm_nt<<<dim3(8, 32), 512, 0, stream>>>(x_bf, wo_bf, nullptr, out,
                                           8192, 2048, 2048);
}

// Round 8
// 710.415 us; speedup vs baseline: 1.1208x; 1.0118x over previous
//
#include <hip/hip_runtime.h>
#include <hip/hip_bf16.h>
#include <cstdint>

// ---------------------------------------------------------------------------
// RNN_11828339933262: h = x @ w_in^T + b_in ; s_t = tanh(s_{t-1} @ W_n + h_t)
//                     y = rmsnorm(s) * norm_weight ; out = y @ w_out^T
// B=4 S=2048 D=2048 N_HEADS=32 HD=64.  All I/O f32; internal GEMMs bf16 MFMA.
// R11: GEMM — R10's 2-phase still drained vmcnt(0) at every __syncthreads
// (compiler barrier semantics), exposing ~600-900cy/K-step; and A-panels were
// re-fetched by all 8 XCDs (~268MB of the 276MB fetch). Fixes:
//  (1) T4 counted vmcnt: raw s_barrier + hand `s_waitcnt vmcnt(4)` waits only
//      for the OLD buffer's 4 loads (issued a full K-step ago); the 4 fresh
//      prefetch loads stay in flight across the barrier. Two raw barriers
//      per K-step (landed-check before reads; read-done before overwrite).
//  (2) XCD remap: id -> (bm-chunk per XCD): XCD k owns bm in [4k,4k+4) x all
//      bn -> A 4MB + B 8MB L2-resident per XCD; fetch ~276 -> ~96MB.
//  (3) T5 setprio(1) around the MFMA cluster.
// ds_read swizzle skipped: [256][32] b128 reads are volume-bound (1KB/instr
// = 8 bank-cycles minimum), conflicts can't exceed that. Scan = R9 (floor).
// ---------------------------------------------------------------------------

typedef short bf16x8 __attribute__((ext_vector_type(8)));   // 8 bf16 = 4 VGPRs
typedef float f32x4 __attribute__((ext_vector_type(4)));
typedef _Float16 f16x2 __attribute__((ext_vector_type(2))); // 1 VGPR

#define GLD16(gp, lp)                                                          \
  __builtin_amdgcn_global_load_lds(                                            \
      (const __attribute__((address_space(1))) void*)(gp),                     \
      (__attribute__((address_space(3))) void*)(lp), 16, 0, 0)

// ---------------------------- f32 -> bf16 convert --------------------------
__global__ __launch_bounds__(256) void cvt_f32_bf16(
    const float* __restrict__ in, __hip_bfloat16* __restrict__ out, int n4) {
  int i = blockIdx.x * 256 + threadIdx.x;
  if (i >= n4) return;
  float4 v = ((const float4*)in)[i];
  __hip_bfloat16 a = __float2bfloat16(v.x);
  __hip_bfloat16 b = __float2bfloat16(v.y);
  __hip_bfloat16 c = __float2bfloat16(v.z);
  __hip_bfloat16 d = __float2bfloat16(v.w);
  ushort4 p;
  p.x = *(unsigned short*)&a; p.y = *(unsigned short*)&b;
  p.z = *(unsigned short*)&c; p.w = *(unsigned short*)&d;
  ((ushort4*)out)[i] = p;
}

// ------------------------------- NT GEMM ------------------------------------
// BM=BN=256, BK=32, 512 threads (8 waves as 2m x 4n), per-wave output 128x64.
// Double-buffered LDS; counted-vmcnt pipeline:
//   iter kt: STAGE(buf^1, kt+1) -> s_waitcnt vmcnt(4) [old buf landed] ->
//            s_barrier -> ds_read buf + MFMA -> s_barrier [reads done,
//            next iter may overwrite buf].
// Raw __builtin_amdgcn_s_barrier (NOT __syncthreads) so the compiler does
// not re-emit a vmcnt(0) drain; fresh loads stay in flight across barriers.
__global__ __launch_bounds__(512) void gemm_nt(
    const __hip_bfloat16* __restrict__ A, const __hip_bfloat16* __restrict__ B,
    const float* __restrict__ bias, float* __restrict__ C,
    int M, int N, int K) {
  __shared__ __hip_bfloat16 As[2][256 * 32];
  __shared__ __hip_bfloat16 Bs[2][256 * 32];
  const int tid  = threadIdx.x;          // 0..511
  const int lane = tid & 63;
  const int wave = tid >> 6;             // 0..7
  const int wm = wave >> 2;              // 0..1  (m half)
  const int wn = wave & 3;               // 0..3  (n quarter)

  // XCD remap (grid 8x32=256, id%8 = XCD round-robin): XCD k owns bm-chunk
  // [4k,4k+4) x all 8 bn -> A (4MB) and B (8MB) both L2-resident per XCD.
  // Bijection: v = (id&7)*32 + (id>>3); bm-tile = v>>3, bn-tile = v&7.
  const int id = blockIdx.y * gridDim.x + blockIdx.x;
  const int v = (id & 7) * 32 + (id >> 3);
  const long bm = (long)(v >> 3) * 256;
  const long bn = (long)(v & 7) * 256;

  // Staging: thread t loads rows r0 = t>>2 and 128+r0, k-chunk (t&3)*8.
  // Linear LDS dest (wave base + lane*16B) == row-major [256][32]:
  // elem w*512 + l*8 == (w*16 + (l>>2))*32 + (l&3)*8.
  const int r0 = tid >> 2;               // 0..127
  const int k0 = (tid & 3) * 8;
  const __hip_bfloat16* gA0 = A + (bm + r0) * (long)K + k0;
  const __hip_bfloat16* gA1 = A + (bm + 128 + r0) * (long)K + k0;
  const __hip_bfloat16* gB0 = B + (bn + r0) * (long)K + k0;
  const __hip_bfloat16* gB1 = B + (bn + 128 + r0) * (long)K + k0;

#define STAGE(sbuf, kt)                                                        \
  do {                                                                         \
    GLD16(gA0 + (kt) * 32, &As[sbuf][wave * 512]);                             \
    GLD16(gA1 + (kt) * 32, &As[sbuf][4096 + wave * 512]);                      \
    GLD16(gB0 + (kt) * 32, &Bs[sbuf][wave * 512]);                             \
    GLD16(gB1 + (kt) * 32, &Bs[sbuf][4096 + wave * 512]);                      \
  } while (0)

  const int fr = lane & 15;
  const int fk = (lane >> 4) * 8;

  f32x4 acc[8][4];
#pragma unroll
  for (int i = 0; i < 8; i++)
#pragma unroll
    for (int j = 0; j < 4; j++) acc[i][j] = {0.f, 0.f, 0.f, 0.f};

  STAGE(0, 0);

  const int nk = K >> 5;                 // 64 K-steps
  for (int kt = 0; kt < nk; kt++) {
    const int cur = kt & 1;
    if (kt + 1 < nk) {
      STAGE(cur ^ 1, kt + 1);            // 4 fresh loads -> 8 outstanding
      asm volatile("s_waitcnt vmcnt(4)" ::: "memory");  // old 4 landed
    } else {
      asm volatile("s_waitcnt vmcnt(0)" ::: "memory");  // last tile: drain
    }
    __builtin_amdgcn_s_barrier();        // all waves: buf[cur] fully landed
    __builtin_amdgcn_sched_barrier(0);   // no hoisting reads above barrier
    bf16x8 af[8], bfr[4];
#pragma unroll
    for (int t = 0; t < 8; t++)
      af[t] = *(const bf16x8*)&As[cur][(wm * 128 + t * 16 + fr) * 32 + fk];
#pragma unroll
    for (int t = 0; t < 4; t++)
      bfr[t] = *(const bf16x8*)&Bs[cur][(wn * 64 + t * 16 + fr) * 32 + fk];
    __builtin_amdgcn_s_setprio(1);
#pragma unroll
    for (int i = 0; i < 8; i++)
#pragma unroll
      for (int j = 0; j < 4; j++)
        acc[i][j] = __builtin_amdgcn_mfma_f32_16x16x32_bf16(
            af[i], bfr[j], acc[i][j], 0, 0, 0);
    __builtin_amdgcn_s_setprio(0);
    __builtin_amdgcn_sched_barrier(0);   // keep reads/MFMA above 2nd barrier
    __builtin_amdgcn_s_barrier();        // reads done -> next iter may stage
  }
#undef STAGE

  const int cr = (lane >> 4) * 4;
  const int cc = lane & 15;
#pragma unroll
  for (int j = 0; j < 4; j++) {
    const long n = bn + wn * 64 + j * 16 + cc;
    const float bv = bias ? bias[n] : 0.0f;
#pragma unroll
    for (int i = 0; i < 8; i++) {
      const long m = bm + wm * 128 + i * 16 + cr;
#pragma unroll
      for (int r = 0; r < 4; r++)
        C[(m + r) * (long)N + n] = acc[i][j][r] + bv;
    }
  }
}

// ------------------------------- RNN scan -----------------------------------
// One wave per (batch, head) chain; lane k owns output k. State broadcast in
// FP16 through a 128-byte LDS buffer: lane writes its new value (b16), then
// all lanes read the full state with 8 ds_read_b128 (same-address broadcast,
// conflict-free). Matvec: 32 v_pk_fma_f16 (via __builtin_elementwise_fma on
// f16x2) against pre-packed fp16 weight pairs held in VGPRs; 4 independent
// accumulator chains. Single-wave block + in-order DS pipe -> no waitcnt
// between write and the broadcast reads. Measured 373us = ~438 cyc/step,
// near the structural floor for this serial-issue chain.
__device__ __forceinline__ float tanh_fast(float z) {
  // tanh(z) = 1 - 2/(e^{2z}+1); e^{2z} = 2^(z * 2*log2(e)) — one mul + v_exp.
  float e = __builtin_amdgcn_exp2f(z * 2.8853900817779268f);
  return 1.0f - 2.0f * __builtin_amdgcn_rcpf(e + 1.0f);
}

__global__ __launch_bounds__(64) void scan_kernel(
    const float* __restrict__ Wst, float* __restrict__ h) {
  const int b = blockIdx.x >> 5;    // 0..3
  const int n = blockIdx.x & 31;    // 0..31
  const int lane = threadIdx.x;     // 0..63
  const float* Wn = Wst + n * 4096; // W[k][j] = Wn[k*64 + j], j contiguous

  // Packed fp16 weight pairs over the contraction dim:
  // w2[p] = (W[2p][lane], W[2p+1][lane]).
  f16x2 w2[32];
#pragma unroll
  for (int p = 0; p < 32; p++) {
    f16x2 t;
    t.x = (_Float16)Wn[(2 * p) * 64 + lane];
    t.y = (_Float16)Wn[(2 * p + 1) * 64 + lane];
    w2[p] = t;
  }

  __shared__ alignas(16) unsigned short s_h[64];  // 128 B fp16 state

  int4 sv[8];
#pragma unroll
  for (int q = 0; q < 8; q++) sv[q] = make_int4(0, 0, 0, 0);

  float* hp = h + ((size_t)b * 2048) * 2048 + n * 64 + lane;  // t-stride 2048
  float xcur[8], xnxt[8];
#pragma unroll
  for (int i = 0; i < 8; i++) xcur[i] = hp[(size_t)i * 2048];

  const f16x2 z2 = {(_Float16)0.f, (_Float16)0.f};

  for (int t0 = 0; t0 < 2048; t0 += 8) {
    if (t0 + 8 < 2048) {
#pragma unroll
      for (int i = 0; i < 8; i++)
        xnxt[i] = hp[(size_t)(t0 + 8 + i) * 2048];
    }
#pragma unroll
    for (int i = 0; i < 8; i++) {
      // z = dot(s_{t-1}, W[:,lane]) + x_t ; 4 independent pk_fma_f16 chains,
      // consumed in read-return order (sv[q] ascending).
      f16x2 ac0 = z2, ac1 = z2, ac2 = z2, ac3 = z2;
#pragma unroll
      for (int q = 0; q < 8; q++) {
        ac0 = __builtin_elementwise_fma(__builtin_bit_cast(f16x2, sv[q].x),
                                        w2[4 * q + 0], ac0);
        ac1 = __builtin_elementwise_fma(__builtin_bit_cast(f16x2, sv[q].y),
                                        w2[4 * q + 1], ac1);
        ac2 = __builtin_elementwise_fma(__builtin_bit_cast(f16x2, sv[q].z),
                                        w2[4 * q + 2], ac2);
        ac3 = __builtin_elementwise_fma(__builtin_bit_cast(f16x2, sv[q].w),
                                        w2[4 * q + 3], ac3);
      }
      f16x2 p01 = ac0 + ac1;             // v_pk_add_f16
      f16x2 p23 = ac2 + ac3;
      f16x2 pt = p01 + p23;
      float z = (float)pt.x + (float)pt.y + xcur[i];
      float sn = tanh_fast(z);
      // Broadcast s_t for step t+1: one b16 write then 8 b128 broadcast
      // reads — DS pipe is in-order per wave, no waitcnt needed between.
      _Float16 sh = (_Float16)sn;
      s_h[lane] = __builtin_bit_cast(unsigned short, sh);
#pragma unroll
      for (int q = 0; q < 8; q++) sv[q] = ((const int4*)s_h)[q];
      hp[(size_t)(t0 + i) * 2048] = sn;   // fire-and-forget, off the path
    }
#pragma unroll
    for (int i = 0; i < 8; i++) xcur[i] = xnxt[i];
  }
}

// --------------------------- RMSNorm -> bf16 --------------------------------
__global__ __launch_bounds__(256) void rmsnorm_to_bf16(
    const float* __restrict__ Y, const float* __restrict__ g,
    __hip_bfloat16* __restrict__ O) {
  const long row = blockIdx.x;
  const float* yr = Y + row * 2048;
  const int tid = threadIdx.x;
  float4 v0 = ((const float4*)yr)[tid * 2];
  float4 v1 = ((const float4*)yr)[tid * 2 + 1];
  float ss = v0.x * v0.x + v0.y * v0.y + v0.z * v0.z + v0.w * v0.w +
             v1.x * v1.x + v1.y * v1.y + v1.z * v1.z + v1.w * v1.w;
#pragma unroll
  for (int off = 32; off > 0; off >>= 1) ss += __shfl_down(ss, off);
  __shared__ float red[4];
  if ((tid & 63) == 0) red[tid >> 6] = ss;
  __syncthreads();
  float inv = rsqrtf((red[0] + red[1] + red[2] + red[3]) * (1.0f / 2048.0f)
                     + 1e-6f);
  float4 g0 = ((const float4*)(g + tid * 8))[0];
  float4 g1 = ((const float4*)(g + tid * 8))[1];
  float ov[8] = {v0.x * inv * g0.x, v0.y * inv * g0.y,
                 v0.z * inv * g0.z, v0.w * inv * g0.w,
                 v1.x * inv * g1.x, v1.y * inv * g1.y,
                 v1.z * inv * g1.z, v1.w * inv * g1.w};
  ushort4 p0, p1;
  __hip_bfloat16 t;
  t = __float2bfloat16(ov[0]); p0.x = *(unsigned short*)&t;
  t = __float2bfloat16(ov[1]); p0.y = *(unsigned short*)&t;
  t = __float2bfloat16(ov[2]); p0.z = *(unsigned short*)&t;
  t = __float2bfloat16(ov[3]); p0.w = *(unsigned short*)&t;
  t = __float2bfloat16(ov[4]); p1.x = *(unsigned short*)&t;
  t = __float2bfloat16(ov[5]); p1.y = *(unsigned short*)&t;
  t = __float2bfloat16(ov[6]); p1.z = *(unsigned short*)&t;
  t = __float2bfloat16(ov[7]); p1.w = *(unsigned short*)&t;
  ushort4* op = (ushort4*)(O + row * 2048 + tid * 8);
  op[0] = p0;
  op[1] = p1;
}

// ------------------------------- launch -------------------------------------
extern "C" void kernel_launch(void* const* d_in, const int* in_sizes, int n_in,
                              void* d_out, int out_size, void* d_ws,
                              size_t ws_size, hipStream_t stream) {
  const float* x     = (const float*)d_in[0];  // (4,2048,2048)
  const float* w_in  = (const float*)d_in[1];  // (2048,2048)
  const float* b_in  = (const float*)d_in[2];  // (2048,)
  const float* w_st  = (const float*)d_in[3];  // (32,64,64)
  const float* nw    = (const float*)d_in[4];  // (2048,)
  const float* w_out = (const float*)d_in[5];  // (2048,2048)
  float* out = (float*)d_out;

  char* ws = (char*)d_ws;
  __hip_bfloat16* x_bf  = (__hip_bfloat16*)(ws);              // 33,554,432 B
  __hip_bfloat16* wi_bf = (__hip_bfloat16*)(ws + 33554432);   //  8,388,608 B
  __hip_bfloat16* wo_bf = (__hip_bfloat16*)(ws + 41943040);   //  8,388,608 B
  float* h              = (float*)(ws + 50331648);            // 67,108,864 B
  // x_bf buffer is reused for the rmsnorm'ed bf16 states (same size).

  cvt_f32_bf16<<<16384, 256, 0, stream>>>(x, x_bf, 4194304);
  cvt_f32_bf16<<<4096, 256, 0, stream>>>(w_in, wi_bf, 1048576);
  cvt_f32_bf16<<<4096, 256, 0, stream>>>(w_out, wo_bf, 1048576);

  // h = x @ w_in^T + b_in   (M=8192, N=2048, K=2048), 256x256 tiles
  gemm_nt<<<dim3(8, 32), 512, 0, stream>>>(x_bf, wi_bf, b_in, h,
                                           8192, 2048, 2048);
  // in-place tanh recurrence per (batch, head)
  scan_kernel<<<128, 64, 0, stream>>>(w_st, h);
  // rmsnorm + cast to bf16 (into x_bf buffer)
  rmsnorm_to_bf16<<<8192, 256, 0, stream>>>(h, nw, x_bf);
  // out = y_norm @ w_out^T
  gemm_nt<<<dim3(8, 32), 512, 0, stream>>>(x_bf, wo_bf, nullptr, out,
                                           8192, 2048, 2048);
}

// Round 9
// 682.403 us; speedup vs baseline: 1.1668x; 1.0410x over previous
//
#include <hip/hip_runtime.h>
#include <hip/hip_bf16.h>
#include <cstdint>

// ---------------------------------------------------------------------------
// RNN_11828339933262: h = x @ w_in^T + b_in ; s_t = tanh(s_{t-1} @ W_n + h_t)
//                     y = rmsnorm(s) * norm_weight ; out = y @ w_out^T
// B=4 S=2048 D=2048 N_HEADS=32 HD=64.  All I/O f32; internal GEMMs bf16 MFMA.
// R12: GEMM — R11 post-mortem: 5475 cyc/K-step vs ~1240 MFMA floor; neither
// vmcnt drain nor HBM explains it. The cost is structural: BK=32 puts tiny
// work between barriers so per-step exposed latency (~3400cy: sync + DS
// latency + all-read-then-all-MFMA serialization) dominates. Fix:
//  (1) BK=64 -> 32 iters, 2x work per sync (24 ds_read + 64 MFMA per wave).
//      LDS 128 KiB (2 dbuf x [256][64] x {A,B}), the m201-proven size.
//  (2) T2 XOR-swizzle, REQUIRED at 128B row stride (else 16-way conflict on
//      banks 0-3). Rule #21: linear gload_lds dest + inverse-swizzled global
//      SOURCE col ((l&7)^((l>>3)&7))*8 + swizzled READ col ^((fr&7)<<3).
//      Round-trip verified on concrete elements.
//  (3) Keep R11's 1-deep pipeline (stage at top, vmcnt(8) waits only the
//      previous tile's 8), 2 raw barriers/iter, setprio, XCD remap.
// Per-acc K order kk0->kk1 == two BK=32 steps -> bit-identical output.
// Scan = R9 (at structural floor, 373us). Scan/cvt/rmsnorm unchanged.
// ---------------------------------------------------------------------------

typedef short bf16x8 __attribute__((ext_vector_type(8)));   // 8 bf16 = 4 VGPRs
typedef float f32x4 __attribute__((ext_vector_type(4)));
typedef _Float16 f16x2 __attribute__((ext_vector_type(2))); // 1 VGPR

#define GLD16(gp, lp)                                                          \
  __builtin_amdgcn_global_load_lds(                                            \
      (const __attribute__((address_space(1))) void*)(gp),                     \
      (__attribute__((address_space(3))) void*)(lp), 16, 0, 0)

// ---------------------------- f32 -> bf16 convert --------------------------
__global__ __launch_bounds__(256) void cvt_f32_bf16(
    const float* __restrict__ in, __hip_bfloat16* __restrict__ out, int n4) {
  int i = blockIdx.x * 256 + threadIdx.x;
  if (i >= n4) return;
  float4 v = ((const float4*)in)[i];
  __hip_bfloat16 a = __float2bfloat16(v.x);
  __hip_bfloat16 b = __float2bfloat16(v.y);
  __hip_bfloat16 c = __float2bfloat16(v.z);
  __hip_bfloat16 d = __float2bfloat16(v.w);
  ushort4 p;
  p.x = *(unsigned short*)&a; p.y = *(unsigned short*)&b;
  p.z = *(unsigned short*)&c; p.w = *(unsigned short*)&d;
  ((ushort4*)out)[i] = p;
}

// ------------------------------- NT GEMM ------------------------------------
// BM=BN=256, BK=64, 512 threads (8 waves as 2m x 4n), per-wave output 128x64.
// Per iter: stage next tile (8 GLD16) -> vmcnt(8) [prev tile landed] ->
// s_barrier -> 24 swizzled ds_read_b128 -> 64 MFMA (setprio) -> s_barrier.
__global__ __launch_bounds__(512, 2) void gemm_nt(
    const __hip_bfloat16* __restrict__ A, const __hip_bfloat16* __restrict__ B,
    const float* __restrict__ bias, float* __restrict__ C,
    int M, int N, int K) {
  __shared__ __hip_bfloat16 As[2][256 * 64];   // 64 KiB
  __shared__ __hip_bfloat16 Bs[2][256 * 64];   // 64 KiB
  const int tid  = threadIdx.x;          // 0..511
  const int lane = tid & 63;
  const int wave = tid >> 6;             // 0..7
  const int wm = wave >> 2;              // 0..1  (m half)
  const int wn = wave & 3;               // 0..3  (n quarter)

  // XCD remap (grid 8x32=256, id%8 = XCD): XCD k owns bm-chunk [4k,4k+4) x
  // all 8 bn. Bijection: v = (id&7)*32 + (id>>3).
  const int id = blockIdx.y * gridDim.x + blockIdx.x;
  const int v = (id & 7) * 32 + (id >> 3);
  const long bm = (long)(v >> 3) * 256;
  const long bn = (long)(v & 7) * 256;

  // Staging (T2 rule #21): LDS dest is LINEAR (wave base + lane*16B ==
  // row-major [256][64]); the swizzle lives in the global SOURCE column:
  // lane l of a 64-row round stages row (wave*8 + l>>3), col chunk
  // ((l&7) ^ ((l>>3)&7))*8  -> LDS byte (row*128 + (l&7)*16) holds logical
  // col ((l&7)*16) ^ ((row&7)<<4). Reads apply the same XOR.
  const int srow = (wave << 3) + (lane >> 3);                  // 0..63
  const int scol = (((lane & 7) ^ ((lane >> 3) & 7)) << 3);    // elems
  const __hip_bfloat16* gA = A + (bm + srow) * (long)K + scol;
  const __hip_bfloat16* gB = B + (bn + srow) * (long)K + scol;
  const long rstep = 64 * (long)K;       // 64-row round stride

#define STAGE(sbuf, kt)                                                        \
  do {                                                                         \
    const long ko_ = (long)(kt) * 64;                                          \
    GLD16(gA + ko_,             &As[sbuf][wave * 512]);                        \
    GLD16(gA + ko_ + rstep,     &As[sbuf][4096 + wave * 512]);                 \
    GLD16(gA + ko_ + 2 * rstep, &As[sbuf][8192 + wave * 512]);                 \
    GLD16(gA + ko_ + 3 * rstep, &As[sbuf][12288 + wave * 512]);                \
    GLD16(gB + ko_,             &Bs[sbuf][wave * 512]);                        \
    GLD16(gB + ko_ + rstep,     &Bs[sbuf][4096 + wave * 512]);                 \
    GLD16(gB + ko_ + 2 * rstep, &Bs[sbuf][8192 + wave * 512]);                 \
    GLD16(gB + ko_ + 3 * rstep, &Bs[sbuf][12288 + wave * 512]);                \
  } while (0)

  const int fr  = lane & 15;
  const int fk8 = (lane >> 4) * 8;
  const int xr  = (fr & 7) << 3;         // read-side swizzle (elems)
  const int ac0 = fk8 ^ xr;              // kk=0 column base
  const int ac1 = (32 + fk8) ^ xr;       // kk=1 column base

  f32x4 acc[8][4];
#pragma unroll
  for (int i = 0; i < 8; i++)
#pragma unroll
    for (int j = 0; j < 4; j++) acc[i][j] = {0.f, 0.f, 0.f, 0.f};

  STAGE(0, 0);
  asm volatile("s_waitcnt vmcnt(0)" ::: "memory");
  __builtin_amdgcn_s_barrier();

  const int nk = K >> 6;                 // 32 K-tiles
  for (int kt = 0; kt < nk; kt++) {
    const int cur = kt & 1;
    if (kt + 1 < nk) {
      STAGE(cur ^ 1, kt + 1);            // 8 fresh -> 16 outstanding
      asm volatile("s_waitcnt vmcnt(8)" ::: "memory");  // prev 8 landed
    } else {
      asm volatile("s_waitcnt vmcnt(0)" ::: "memory");
    }
    __builtin_amdgcn_s_barrier();        // buf[cur] fully landed, all waves
    __builtin_amdgcn_sched_barrier(0);   // no hoisting reads above barrier
    bf16x8 af[8][2], bfr[4][2];
#pragma unroll
    for (int t = 0; t < 8; t++) {
      const int rb = (wm * 128 + t * 16 + fr) * 64;
      af[t][0] = *(const bf16x8*)&As[cur][rb + ac0];
      af[t][1] = *(const bf16x8*)&As[cur][rb + ac1];
    }
#pragma unroll
    for (int j = 0; j < 4; j++) {
      const int rb = (wn * 64 + j * 16 + fr) * 64;
      bfr[j][0] = *(const bf16x8*)&Bs[cur][rb + ac0];
      bfr[j][1] = *(const bf16x8*)&Bs[cur][rb + ac1];
    }
    __builtin_amdgcn_s_setprio(1);
#pragma unroll
    for (int i = 0; i < 8; i++)
#pragma unroll
      for (int j = 0; j < 4; j++) {
        acc[i][j] = __builtin_amdgcn_mfma_f32_16x16x32_bf16(
            af[i][0], bfr[j][0], acc[i][j], 0, 0, 0);
        acc[i][j] = __builtin_amdgcn_mfma_f32_16x16x32_bf16(
            af[i][1], bfr[j][1], acc[i][j], 0, 0, 0);
      }
    __builtin_amdgcn_s_setprio(0);
    __builtin_amdgcn_sched_barrier(0);   // keep reads/MFMA above 2nd barrier
    __builtin_amdgcn_s_barrier();        // reads done -> next iter may stage
  }
#undef STAGE

  const int cr = (lane >> 4) * 4;
  const int cc = lane & 15;
#pragma unroll
  for (int j = 0; j < 4; j++) {
    const long n = bn + wn * 64 + j * 16 + cc;
    const float bv = bias ? bias[n] : 0.0f;
#pragma unroll
    for (int i = 0; i < 8; i++) {
      const long m = bm + wm * 128 + i * 16 + cr;
#pragma unroll
      for (int r = 0; r < 4; r++)
        C[(m + r) * (long)N + n] = acc[i][j][r] + bv;
    }
  }
}

// ------------------------------- RNN scan -----------------------------------
// One wave per (batch, head) chain; lane k owns output k. State broadcast in
// FP16 through a 128-byte LDS buffer: lane writes its new value (b16), then
// all lanes read the full state with 8 ds_read_b128 (same-address broadcast,
// conflict-free). Matvec: 32 v_pk_fma_f16 (via __builtin_elementwise_fma on
// f16x2) against pre-packed fp16 weight pairs held in VGPRs; 4 independent
// accumulator chains. Single-wave block + in-order DS pipe -> no waitcnt
// between write and the broadcast reads. Measured 373us = ~438 cyc/step,
// at the structural floor for this serial-issue chain.
__device__ __forceinline__ float tanh_fast(float z) {
  // tanh(z) = 1 - 2/(e^{2z}+1); e^{2z} = 2^(z * 2*log2(e)) — one mul + v_exp.
  float e = __builtin_amdgcn_exp2f(z * 2.8853900817779268f);
  return 1.0f - 2.0f * __builtin_amdgcn_rcpf(e + 1.0f);
}

__global__ __launch_bounds__(64) void scan_kernel(
    const float* __restrict__ Wst, float* __restrict__ h) {
  const int b = blockIdx.x >> 5;    // 0..3
  const int n = blockIdx.x & 31;    // 0..31
  const int lane = threadIdx.x;     // 0..63
  const float* Wn = Wst + n * 4096; // W[k][j] = Wn[k*64 + j], j contiguous

  // Packed fp16 weight pairs over the contraction dim:
  // w2[p] = (W[2p][lane], W[2p+1][lane]).
  f16x2 w2[32];
#pragma unroll
  for (int p = 0; p < 32; p++) {
    f16x2 t;
    t.x = (_Float16)Wn[(2 * p) * 64 + lane];
    t.y = (_Float16)Wn[(2 * p + 1) * 64 + lane];
    w2[p] = t;
  }

  __shared__ alignas(16) unsigned short s_h[64];  // 128 B fp16 state

  int4 sv[8];
#pragma unroll
  for (int q = 0; q < 8; q++) sv[q] = make_int4(0, 0, 0, 0);

  float* hp = h + ((size_t)b * 2048) * 2048 + n * 64 + lane;  // t-stride 2048
  float xcur[8], xnxt[8];
#pragma unroll
  for (int i = 0; i < 8; i++) xcur[i] = hp[(size_t)i * 2048];

  const f16x2 z2 = {(_Float16)0.f, (_Float16)0.f};

  for (int t0 = 0; t0 < 2048; t0 += 8) {
    if (t0 + 8 < 2048) {
#pragma unroll
      for (int i = 0; i < 8; i++)
        xnxt[i] = hp[(size_t)(t0 + 8 + i) * 2048];
    }
#pragma unroll
    for (int i = 0; i < 8; i++) {
      // z = dot(s_{t-1}, W[:,lane]) + x_t ; 4 independent pk_fma_f16 chains,
      // consumed in read-return order (sv[q] ascending).
      f16x2 ac0 = z2, ac1 = z2, ac2 = z2, ac3 = z2;
#pragma unroll
      for (int q = 0; q < 8; q++) {
        ac0 = __builtin_elementwise_fma(__builtin_bit_cast(f16x2, sv[q].x),
                                        w2[4 * q + 0], ac0);
        ac1 = __builtin_elementwise_fma(__builtin_bit_cast(f16x2, sv[q].y),
                                        w2[4 * q + 1], ac1);
        ac2 = __builtin_elementwise_fma(__builtin_bit_cast(f16x2, sv[q].z),
                                        w2[4 * q + 2], ac2);
        ac3 = __builtin_elementwise_fma(__builtin_bit_cast(f16x2, sv[q].w),
                                        w2[4 * q + 3], ac3);
      }
      f16x2 p01 = ac0 + ac1;             // v_pk_add_f16
      f16x2 p23 = ac2 + ac3;
      f16x2 pt = p01 + p23;
      float z = (float)pt.x + (float)pt.y + xcur[i];
      float sn = tanh_fast(z);
      // Broadcast s_t for step t+1: one b16 write then 8 b128 broadcast
      // reads — DS pipe is in-order per wave, no waitcnt needed between.
      _Float16 sh = (_Float16)sn;
      s_h[lane] = __builtin_bit_cast(unsigned short, sh);
#pragma unroll
      for (int q = 0; q < 8; q++) sv[q] = ((const int4*)s_h)[q];
      hp[(size_t)(t0 + i) * 2048] = sn;   // fire-and-forget, off the path
    }
#pragma unroll
    for (int i = 0; i < 8; i++) xcur[i] = xnxt[i];
  }
}

// --------------------------- RMSNorm -> bf16 --------------------------------
__global__ __launch_bounds__(256) void rmsnorm_to_bf16(
    const float* __restrict__ Y, const float* __restrict__ g,
    __hip_bfloat16* __restrict__ O) {
  const long row = blockIdx.x;
  const float* yr = Y + row * 2048;
  const int tid = threadIdx.x;
  float4 v0 = ((const float4*)yr)[tid * 2];
  float4 v1 = ((const float4*)yr)[tid * 2 + 1];
  float ss = v0.x * v0.x + v0.y * v0.y + v0.z * v0.z + v0.w * v0.w +
             v1.x * v1.x + v1.y * v1.y + v1.z * v1.z + v1.w * v1.w;
#pragma unroll
  for (int off = 32; off > 0; off >>= 1) ss += __shfl_down(ss, off);
  __shared__ float red[4];
  if ((tid & 63) == 0) red[tid >> 6] = ss;
  __syncthreads();
  float inv = rsqrtf((red[0] + red[1] + red[2] + red[3]) * (1.0f / 2048.0f)
                     + 1e-6f);
  float4 g0 = ((const float4*)(g + tid * 8))[0];
  float4 g1 = ((const float4*)(g + tid * 8))[1];
  float ov[8] = {v0.x * inv * g0.x, v0.y * inv * g0.y,
                 v0.z * inv * g0.z, v0.w * inv * g0.w,
                 v1.x * inv * g1.x, v1.y * inv * g1.y,
                 v1.z * inv * g1.z, v1.w * inv * g1.w};
  ushort4 p0, p1;
  __hip_bfloat16 t;
  t = __float2bfloat16(ov[0]); p0.x = *(unsigned short*)&t;
  t = __float2bfloat16(ov[1]); p0.y = *(unsigned short*)&t;
  t = __float2bfloat16(ov[2]); p0.z = *(unsigned short*)&t;
  t = __float2bfloat16(ov[3]); p0.w = *(unsigned short*)&t;
  t = __float2bfloat16(ov[4]); p1.x = *(unsigned short*)&t;
  t = __float2bfloat16(ov[5]); p1.y = *(unsigned short*)&t;
  t = __float2bfloat16(ov[6]); p1.z = *(unsigned short*)&t;
  t = __float2bfloat16(ov[7]); p1.w = *(unsigned short*)&t;
  ushort4* op = (ushort4*)(O + row * 2048 + tid * 8);
  op[0] = p0;
  op[1] = p1;
}

// ------------------------------- launch -------------------------------------
extern "C" void kernel_launch(void* const* d_in, const int* in_sizes, int n_in,
                              void* d_out, int out_size, void* d_ws,
                              size_t ws_size, hipStream_t stream) {
  const float* x     = (const float*)d_in[0];  // (4,2048,2048)
  const float* w_in  = (const float*)d_in[1];  // (2048,2048)
  const float* b_in  = (const float*)d_in[2];  // (2048,)
  const float* w_st  = (const float*)d_in[3];  // (32,64,64)
  const float* nw    = (const float*)d_in[4];  // (2048,)
  const float* w_out = (const float*)d_in[5];  // (2048,2048)
  float* out = (float*)d_out;

  char* ws = (char*)d_ws;
  __hip_bfloat16* x_bf  = (__hip_bfloat16*)(ws);              // 33,554,432 B
  __hip_bfloat16* wi_bf = (__hip_bfloat16*)(ws + 33554432);   //  8,388,608 B
  __hip_bfloat16* wo_bf = (__hip_bfloat16*)(ws + 41943040);   //  8,388,608 B
  float* h              = (float*)(ws + 50331648);            // 67,108,864 B
  // x_bf buffer is reused for the rmsnorm'ed bf16 states (same size).

  cvt_f32_bf16<<<16384, 256, 0, stream>>>(x, x_bf, 4194304);
  cvt_f32_bf16<<<4096, 256, 0, stream>>>(w_in, wi_bf, 1048576);
  cvt_f32_bf16<<<4096, 256, 0, stream>>>(w_out, wo_bf, 1048576);

  // h = x @ w_in^T + b_in   (M=8192, N=2048, K=2048), 256x256 tiles, BK=64
  gemm_nt<<<dim3(8, 32), 512, 0, stream>>>(x_bf, wi_bf, b_in, h,
                                           8192, 2048, 2048);
  // in-place tanh recurrence per (batch, head)
  scan_kernel<<<128, 64, 0, stream>>>(w_st, h);
  // rmsnorm + cast to bf16 (into x_bf buffer)
  rmsnorm_to_bf16<<<8192, 256, 0, stream>>>(h, nw, x_bf);
  // out = y_norm @ w_out^T
  gemm_nt<<<dim3(8, 32), 512, 0, stream>>>(x_bf, wo_bf, nullptr, out,
                                           8192, 2048, 2048);
}